// Round 1
// baseline (2367.395 us; speedup 1.0000x reference)
//
#include <hip/hip_runtime.h>
#include <hip/hip_bf16.h>

#define B_ 256
#define T_ 2048
#define I_ 64
#define H_ 128
#define G_ 384   // 3*H
#define O_ 10

typedef _Float16 half2_t __attribute__((ext_vector_type(2)));

__device__ __forceinline__ float sigm_(float s) {
  s = fminf(fmaxf(s, -30.f), 30.f);
  return __builtin_amdgcn_rcpf(1.f + __expf(-s));
}
// tanh(s) = 1 - 2/(1+e^{2s})
__device__ __forceinline__ float tanh_(float s) {
  s = fminf(fmaxf(s, -15.f), 15.f);
  return 1.f - 2.f * __builtin_amdgcn_rcpf(1.f + __expf(2.f * s));
}

__global__ __launch_bounds__(768) void gru_net(
    const float* __restrict__ x,
    const float* __restrict__ Wih0, const float* __restrict__ Whh0,
    const float* __restrict__ bih0, const float* __restrict__ bhh0,
    const float* __restrict__ Wih1, const float* __restrict__ Whh1,
    const float* __restrict__ bih1, const float* __restrict__ bhh1,
    const float* __restrict__ fcW, const float* __restrict__ fcb,
    float* __restrict__ out)
{
  const int b   = blockIdx.x;
  const int tid = threadIdx.x;

  __shared__ alignas(16) half2_t xp[2][I_/2];    // x_t as fp16 pairs, double-buffered
  __shared__ alignas(16) half2_t h0p[2][H_/2];   // h0 fp16, double-buffered
  __shared__ alignas(16) half2_t h1p[2][H_/2];   // h1 fp16, double-buffered
  __shared__ float h0f[H_], h1f[H_];             // fp32 hidden states
  __shared__ float rz0[2*H_], rz1[2*H_];         // r,z gate values

  const size_t xbase = (size_t)b * T_ * I_;

  // ---- init shared state ----
  if (tid < H_) { h0f[tid] = 0.f; h1f[tid] = 0.f; }
  if (tid < H_/2) {
    half2_t z2; z2[0] = (_Float16)0.f; z2[1] = (_Float16)0.f;
    h0p[0][tid] = z2; h0p[1][tid] = z2;
    h1p[0][tid] = z2; h1p[1][tid] = z2;
  }
  if (tid < I_) {
    ((_Float16*)xp[0])[tid] = (_Float16)x[xbase + tid];
  }
  __syncthreads();

  if (tid < G_) {
    // =================== layer-0 role: thread = gate g ===================
    const int g = tid;
    half2_t wi[I_/2], wh[H_/2];
    {
      const float* p0 = Wih0 + (size_t)g * I_;
      #pragma unroll
      for (int k = 0; k < I_/2; ++k) {
        half2_t w; w[0] = (_Float16)p0[2*k]; w[1] = (_Float16)p0[2*k+1]; wi[k] = w;
      }
      const float* p1 = Whh0 + (size_t)g * H_;
      #pragma unroll
      for (int k = 0; k < H_/2; ++k) {
        half2_t w; w[0] = (_Float16)p1[2*k]; w[1] = (_Float16)p1[2*k+1]; wh[k] = w;
      }
    }
    const float bi = bih0[g], bh = bhh0[g];

    for (int p = 0; p <= T_; ++p) {
      float ax = 0.f, ah = 0.f, xnext = 0.f;
      const bool act = (p < T_);
      if (act) {
        if (g < I_ && p + 1 < T_) xnext = x[xbase + (size_t)(p + 1) * I_ + g];
        const half2_t* xr = xp[p & 1];
        const half2_t* hr = h0p[(p & 1) ^ 1];
        float a0 = 0.f, a1 = 0.f, a2 = 0.f, a3 = 0.f;
        #pragma unroll
        for (int k = 0; k < I_/2; k += 4) {
          a0 = __builtin_amdgcn_fdot2(wi[k+0], xr[k+0], a0, false);
          a1 = __builtin_amdgcn_fdot2(wi[k+1], xr[k+1], a1, false);
          a2 = __builtin_amdgcn_fdot2(wi[k+2], xr[k+2], a2, false);
          a3 = __builtin_amdgcn_fdot2(wi[k+3], xr[k+3], a3, false);
        }
        ax = bi + ((a0 + a1) + (a2 + a3));
        float c0 = 0.f, c1 = 0.f, c2 = 0.f, c3 = 0.f;
        #pragma unroll
        for (int k = 0; k < H_/2; k += 4) {
          c0 = __builtin_amdgcn_fdot2(wh[k+0], hr[k+0], c0, false);
          c1 = __builtin_amdgcn_fdot2(wh[k+1], hr[k+1], c1, false);
          c2 = __builtin_amdgcn_fdot2(wh[k+2], hr[k+2], c2, false);
          c3 = __builtin_amdgcn_fdot2(wh[k+3], hr[k+3], c3, false);
        }
        ah = bh + ((c0 + c1) + (c2 + c3));
        if (g < 2*H_) rz0[g] = sigm_(ax + ah);
      }
      __syncthreads();                       // B2: r,z ready
      if (act) {
        if (g >= 2*H_) {
          const int j = g - 2*H_;
          const float r = rz0[j], z = rz0[H_ + j];
          const float n = tanh_(ax + r * ah);
          const float hn = z * (h0f[j] - n) + n;   // (1-z)*n + z*h
          h0f[j] = hn;
          ((_Float16*)h0p[p & 1])[j] = (_Float16)hn;
        }
        if (g < I_ && p + 1 < T_)
          ((_Float16*)xp[(p + 1) & 1])[g] = (_Float16)xnext;
      }
      __syncthreads();                       // B3: phase end
    }
  } else {
    // =================== layer-1 role: thread = gate g (lag 1 step) ===================
    const int g = tid - G_;
    half2_t wi[H_/2], wh[H_/2];
    {
      const float* p0 = Wih1 + (size_t)g * H_;
      #pragma unroll
      for (int k = 0; k < H_/2; ++k) {
        half2_t w; w[0] = (_Float16)p0[2*k]; w[1] = (_Float16)p0[2*k+1]; wi[k] = w;
      }
      const float* p1 = Whh1 + (size_t)g * H_;
      #pragma unroll
      for (int k = 0; k < H_/2; ++k) {
        half2_t w; w[0] = (_Float16)p1[2*k]; w[1] = (_Float16)p1[2*k+1]; wh[k] = w;
      }
    }
    const float bi = bih1[g], bh = bhh1[g];

    for (int p = 0; p <= T_; ++p) {
      float ax = 0.f, ah = 0.f;
      const bool act = (p >= 1);
      if (act) {
        const half2_t* h0r = h0p[(p & 1) ^ 1];   // h0(p-1), written in phase p-1
        const half2_t* h1r = h1p[(p & 1) ^ 1];   // h1(p-2), written in phase p-1
        float a0 = 0.f, a1 = 0.f, a2 = 0.f, a3 = 0.f;
        #pragma unroll
        for (int k = 0; k < H_/2; k += 4) {
          a0 = __builtin_amdgcn_fdot2(wi[k+0], h0r[k+0], a0, false);
          a1 = __builtin_amdgcn_fdot2(wi[k+1], h0r[k+1], a1, false);
          a2 = __builtin_amdgcn_fdot2(wi[k+2], h0r[k+2], a2, false);
          a3 = __builtin_amdgcn_fdot2(wi[k+3], h0r[k+3], a3, false);
        }
        ax = bi + ((a0 + a1) + (a2 + a3));
        float c0 = 0.f, c1 = 0.f, c2 = 0.f, c3 = 0.f;
        #pragma unroll
        for (int k = 0; k < H_/2; k += 4) {
          c0 = __builtin_amdgcn_fdot2(wh[k+0], h1r[k+0], c0, false);
          c1 = __builtin_amdgcn_fdot2(wh[k+1], h1r[k+1], c1, false);
          c2 = __builtin_amdgcn_fdot2(wh[k+2], h1r[k+2], c2, false);
          c3 = __builtin_amdgcn_fdot2(wh[k+3], h1r[k+3], c3, false);
        }
        ah = bh + ((c0 + c1) + (c2 + c3));
        if (g < 2*H_) rz1[g] = sigm_(ax + ah);
      }
      __syncthreads();                       // B2
      if (act && g >= 2*H_) {
        const int j = g - 2*H_;
        const float r = rz1[j], z = rz1[H_ + j];
        const float n = tanh_(ax + r * ah);
        const float hn = z * (h1f[j] - n) + n;
        h1f[j] = hn;
        ((_Float16*)h1p[p & 1])[j] = (_Float16)hn;
      }
      __syncthreads();                       // B3
    }
  }

  // ---- final FC on h1(T-1) ----
  if (tid < O_) {
    float acc = fcb[tid];
    const float* wr = fcW + (size_t)tid * H_;
    #pragma unroll 8
    for (int k = 0; k < H_; ++k) acc = fmaf(h1f[k], wr[k], acc);
    out[(size_t)b * O_ + tid] = acc;
  }
}

extern "C" void kernel_launch(void* const* d_in, const int* in_sizes, int n_in,
                              void* d_out, int out_size, void* d_ws, size_t ws_size,
                              hipStream_t stream) {
  const float* x    = (const float*)d_in[0];
  const float* Wih0 = (const float*)d_in[1];
  const float* Whh0 = (const float*)d_in[2];
  const float* bih0 = (const float*)d_in[3];
  const float* bhh0 = (const float*)d_in[4];
  const float* Wih1 = (const float*)d_in[5];
  const float* Whh1 = (const float*)d_in[6];
  const float* bih1 = (const float*)d_in[7];
  const float* bhh1 = (const float*)d_in[8];
  const float* fcW  = (const float*)d_in[9];
  const float* fcb  = (const float*)d_in[10];

  gru_net<<<dim3(B_), dim3(768), 0, stream>>>(
      x, Wih0, Whh0, bih0, bhh0, Wih1, Whh1, bih1, bhh1, fcW, fcb,
      (float*)d_out);
}